// Round 24
// baseline (68.539 us; speedup 1.0000x reference)
//
#include <hip/hip_runtime.h>

#define B_  2
#define TQ  1024
#define TV  1024
#define DD  512
#define UU  128

#define QB  4            // q-rows per fused block

typedef __attribute__((ext_vector_type(8))) short short8;
typedef __attribute__((ext_vector_type(4))) float f32x4;
typedef __attribute__((ext_vector_type(2))) float f32x2;

__device__ __forceinline__ unsigned short f2bf(float x){
    unsigned int u = __float_as_uint(x);
    unsigned int r = (u + 0x7FFFu + ((u >> 16) & 1u)) >> 16;
    return (unsigned short)r;
}
__device__ __forceinline__ float bf2f(unsigned short h){
    return __uint_as_float(((unsigned int)h) << 16);
}

// ---------------- W transpose + bf16 h/l split (tiny, runs first) ----------------
__global__ __launch_bounds__(256)
void wsplit_kernel(const float* __restrict__ W1, const float* __restrict__ W2,
                   unsigned short* __restrict__ wth, unsigned short* __restrict__ wtl){
    __shared__ float t[64][65];
    const int wb  = blockIdx.x;
    const int qk  = wb >> 4;
    const int rem = wb & 15;
    const int k0  = (rem >> 1) * 64;
    const int u0  = (rem & 1) * 64;
    const float* W = qk ? W2 : W1;
    const int tid = threadIdx.x;

    #pragma unroll
    for (int i = 0; i < 4; ++i){
        int r = (tid >> 4) + 16*i;
        int c = (tid & 15) * 4;
        float4 v = *reinterpret_cast<const float4*>(W + (size_t)(k0 + r)*UU + u0 + c);
        t[r][c+0]=v.x; t[r][c+1]=v.y; t[r][c+2]=v.z; t[r][c+3]=v.w;
    }
    __syncthreads();

    const int dr = tid >> 2;
    const int kc = (tid & 3) * 16;
    #pragma unroll
    for (int g = 0; g < 2; ++g){
        unsigned short h8[8], l8[8];
        #pragma unroll
        for (int e = 0; e < 8; ++e){
            float v = t[kc + g*8 + e][dr];
            unsigned short h = f2bf(v);
            h8[e] = h; l8[e] = f2bf(v - bf2f(h));
        }
        size_t o = ((size_t)qk*UU + u0 + dr)*(size_t)DD + k0 + kc + g*8;
        *reinterpret_cast<int4*>(wth + o) = *reinterpret_cast<const int4*>(h8);
        *reinterpret_cast<int4*>(wtl + o) = *reinterpret_cast<const int4*>(l8);
    }
}

// ---------------- merged: vsplit (blocks 0..255) + projm (blocks 256..767) ----------------
__global__ __launch_bounds__(256, 4)
void projv_kernel(const float* __restrict__ query, const float* __restrict__ value,
                  const unsigned short* __restrict__ wth, const unsigned short* __restrict__ wtl,
                  unsigned short* __restrict__ vht, unsigned short* __restrict__ vlt,
                  float* __restrict__ eq, float* __restrict__ ek){
    __shared__ char smem[20608];
    const int bid = blockIdx.x;
    const int tid = threadIdx.x;

    if (bid < 256){
        // ---- vsplit ----
        float (*t)[65] = reinterpret_cast<float(*)[65]>(smem);
        const int b   = bid >> 7;
        const int rem = bid & 127;
        const int k0  = (rem >> 3) * 64;
        const int d0  = (rem & 7) * 64;

        #pragma unroll
        for (int i = 0; i < 4; ++i){
            int r = (tid >> 4) + 16*i;
            int c = (tid & 15) * 4;
            float4 v = *reinterpret_cast<const float4*>(value + ((size_t)b*TV + k0 + r)*DD + d0 + c);
            t[r][c+0]=v.x; t[r][c+1]=v.y; t[r][c+2]=v.z; t[r][c+3]=v.w;
        }
        __syncthreads();

        const int dr = tid >> 2;
        const int kc = (tid & 3) * 16;
        #pragma unroll
        for (int g = 0; g < 2; ++g){
            unsigned short h8[8], l8[8];
            #pragma unroll
            for (int e = 0; e < 8; ++e){
                float v = t[kc + g*8 + e][dr];
                unsigned short h = f2bf(v);
                h8[e] = h; l8[e] = f2bf(v - bf2f(h));
            }
            size_t o = ((size_t)b*DD + d0 + dr)*(size_t)TV + k0 + kc + g*8;
            *reinterpret_cast<int4*>(vht + o) = *reinterpret_cast<const int4*>(h8);
            *reinterpret_cast<int4*>(vlt + o) = *reinterpret_cast<const int4*>(l8);
        }
        return;
    }

    // ---- projm ----
    unsigned short* Ah = reinterpret_cast<unsigned short*>(smem);
    unsigned short* Al = Ah + 16*64;
    unsigned short* Bh = Al + 16*64;
    unsigned short* Bl = Bh + 64*64;

    const float TWO_LOG2E = 2.8853900817779268f;
    const int pb  = bid - 256;
    const int qk  = pb >> 8;
    const int rem = pb & 255;
    const int r0g = (rem >> 1) * 16;
    const int n0  = (rem & 1) * 64;
    const float* X = qk ? value : query;
    float* out     = qk ? ek    : eq;
    const unsigned short* WH = wth + (size_t)qk * UU * DD;
    const unsigned short* WL = wtl + (size_t)qk * UU * DD;

    const int lane = tid & 63;
    const int w    = tid >> 6;

    const int ar  = tid >> 4;
    const int akq = (tid & 15) * 4;
    const int bc  = tid >> 2;
    const int bkc = (tid & 3) * 16;

    const float*          xrow  = X + (size_t)(r0g + ar) * DD;
    const unsigned short* whrow = WH + (size_t)(n0 + bc) * DD;
    const unsigned short* wlrow = WL + (size_t)(n0 + bc) * DD;

    float4 ra = *reinterpret_cast<const float4*>(xrow + akq);
    int4 rwh0 = *reinterpret_cast<const int4*>(whrow + bkc);
    int4 rwh1 = *reinterpret_cast<const int4*>(whrow + bkc + 8);
    int4 rwl0 = *reinterpret_cast<const int4*>(wlrow + bkc);
    int4 rwl1 = *reinterpret_cast<const int4*>(wlrow + bkc + 8);

    f32x4 acc = (f32x4){0.f,0.f,0.f,0.f};

    const int ga  = (akq >> 3) ^ (ar & 7);
    const int ao  = akq & 7;
    const int gb0 = ((bkc >> 3) + 0) ^ (bc & 7);
    const int gb1 = ((bkc >> 3) + 1) ^ (bc & 7);

    for (int kt = 0; kt < DD; kt += 64){
        {
            unsigned short h4[4], l4[4];
            #pragma unroll
            for (int e = 0; e < 4; ++e){
                float a = (e==0)?ra.x:(e==1)?ra.y:(e==2)?ra.z:ra.w;
                unsigned short h = f2bf(a);
                h4[e] = h; l4[e] = f2bf(a - bf2f(h));
            }
            *reinterpret_cast<int2*>(&Ah[ar*64 + ga*8 + ao]) = *reinterpret_cast<const int2*>(h4);
            *reinterpret_cast<int2*>(&Al[ar*64 + ga*8 + ao]) = *reinterpret_cast<const int2*>(l4);
        }
        *reinterpret_cast<int4*>(&Bh[bc*64 + gb0*8]) = rwh0;
        *reinterpret_cast<int4*>(&Bh[bc*64 + gb1*8]) = rwh1;
        *reinterpret_cast<int4*>(&Bl[bc*64 + gb0*8]) = rwl0;
        *reinterpret_cast<int4*>(&Bl[bc*64 + gb1*8]) = rwl1;

        const int ktn = (kt + 64 < DD) ? kt + 64 : 0;
        ra   = *reinterpret_cast<const float4*>(xrow + ktn + akq);
        rwh0 = *reinterpret_cast<const int4*>(whrow + ktn + bkc);
        rwh1 = *reinterpret_cast<const int4*>(whrow + ktn + bkc + 8);
        rwl0 = *reinterpret_cast<const int4*>(wlrow + ktn + bkc);
        rwl1 = *reinterpret_cast<const int4*>(wlrow + ktn + bkc + 8);

        __syncthreads();

        #pragma unroll
        for (int kk = 0; kk < 2; ++kk){
            const int kg = kk*4 + (lane >> 4);
            const int g  = (kg ^ (lane & 7)) * 8;
            const int r0 = (lane & 15) * 64;
            const int c0 = (w*16 + (lane & 15)) * 64;

            short8 ah = *reinterpret_cast<const short8*>(&Ah[r0 + g]);
            short8 al = *reinterpret_cast<const short8*>(&Al[r0 + g]);
            short8 bh = *reinterpret_cast<const short8*>(&Bh[c0 + g]);
            short8 bl = *reinterpret_cast<const short8*>(&Bl[c0 + g]);

            acc = __builtin_amdgcn_mfma_f32_16x16x32_bf16(ah, bh, acc, 0, 0, 0);
            acc = __builtin_amdgcn_mfma_f32_16x16x32_bf16(al, bh, acc, 0, 0, 0);
            acc = __builtin_amdgcn_mfma_f32_16x16x32_bf16(ah, bl, acc, 0, 0, 0);
        }

        __syncthreads();
    }

    const int orow = r0g + (lane >> 4) * 4;
    const int ocol = n0 + w*16 + (lane & 15);
    #pragma unroll
    for (int r = 0; r < 4; ++r)
        out[(size_t)(orow + r) * UU + ocol] = __builtin_amdgcn_exp2f(TWO_LOG2E * acc[r]);
}

// ---------------- fused scores + softmax, packed f32x2 math + q-prefetch ----------------
// score[q,k] = -2 * sum_u scale[u] * rcp(1 + EQ[q,u]*EK[k,u])  (+const, cancels in softmax)
__global__ __launch_bounds__(1024, 8)
void fused_kernel(const float* __restrict__ eq, const float* __restrict__ ek,
                  const float* __restrict__ scale, float* __restrict__ attn){
    __shared__ float sm[QB][TV];
    __shared__ float psum[QB][4];

    const float LOG2E = 1.4426950408889634f;
    const int b   = blockIdx.y;
    const int q0  = blockIdx.x * QB;
    const int tid = threadIdx.x;
    const int w   = tid >> 6, lane = tid & 63;

    const f32x2* q0v = reinterpret_cast<const f32x2*>(eq + ((size_t)b * TQ + q0 + 0) * UU);
    const f32x2* q1v = reinterpret_cast<const f32x2*>(eq + ((size_t)b * TQ + q0 + 1) * UU);
    const f32x2* q2v = reinterpret_cast<const f32x2*>(eq + ((size_t)b * TQ + q0 + 2) * UU);
    const f32x2* q3v = reinterpret_cast<const f32x2*>(eq + ((size_t)b * TQ + q0 + 3) * UU);
    const f32x2* sc2 = reinterpret_cast<const f32x2*>(scale);

    const float4* ekv = reinterpret_cast<const float4*>(ek + (size_t)b * TV * UU);

    const int kA = w*64 + lane;
    const size_t iA = (size_t)kA * 32;

    f32x2 acc2[QB];
    #pragma unroll
    for (int r = 0; r < QB; ++r) acc2[r] = (f32x2){0.f, 0.f};
    const f32x2 one2 = (f32x2){1.0f, 1.0f};

    float4 kva = ekv[iA];
    f32x2 qc[QB][2];
    #pragma unroll
    for (int r = 0; r < QB; ++r){
        const f32x2* qv = (r==0)?q0v:(r==1)?q1v:(r==2)?q2v:q3v;
        qc[r][0] = qv[0];
        qc[r][1] = qv[1];
    }

    for (int j = 0; j < 32; ++j){
        float4 nka;
        f32x2 qn[QB][2];
        if (j != 31){
            nka = ekv[iA + j + 1];
            #pragma unroll
            for (int r = 0; r < QB; ++r){
                const f32x2* qv = (r==0)?q0v:(r==1)?q1v:(r==2)?q2v:q3v;
                qn[r][0] = qv[2*(j+1)];
                qn[r][1] = qv[2*(j+1)+1];
            }
        }
        f32x2 sxy = sc2[2*j], szw = sc2[2*j+1];
        f32x2 kxy, kzw;
        kxy.x = kva.x; kxy.y = kva.y;
        kzw.x = kva.z; kzw.y = kva.w;
        #pragma unroll
        for (int r = 0; r < QB; ++r){
            f32x2 t, rr;
            t = qc[r][0] * kxy + one2;
            rr.x = __builtin_amdgcn_rcpf(t.x);
            rr.y = __builtin_amdgcn_rcpf(t.y);
            acc2[r] += sxy * rr;
            t = qc[r][1] * kzw + one2;
            rr.x = __builtin_amdgcn_rcpf(t.x);
            rr.y = __builtin_amdgcn_rcpf(t.y);
            acc2[r] += szw * rr;
        }
        kva = nka;
        #pragma unroll
        for (int r = 0; r < QB; ++r){
            qc[r][0] = qn[r][0];
            qc[r][1] = qn[r][1];
        }
    }

    #pragma unroll
    for (int r = 0; r < QB; ++r) sm[r][kA] = -2.0f * (acc2[r].x + acc2[r].y);
    __syncthreads();

    // no-max softmax: wave w -> row r = w&3, segment seg = w>>2 (256 k)
    {
        const int r   = w & 3;
        const int seg = w >> 2;
        float s[4];
        #pragma unroll
        for (int t = 0; t < 4; ++t) s[t] = sm[r][seg*256 + t*64 + lane];

        float sum = 0.f;
        #pragma unroll
        for (int t = 0; t < 4; ++t){ s[t] = __builtin_amdgcn_exp2f(s[t] * LOG2E); sum += s[t]; }
        #pragma unroll
        for (int off = 32; off >= 1; off >>= 1) sum += __shfl_xor(sum, off, 64);
        if (lane == 0) psum[r][seg] = sum;
        __syncthreads();

        float S = (psum[r][0] + psum[r][1]) + (psum[r][2] + psum[r][3]);
        float inv = 1.0f / S;

        float* arow = attn + ((size_t)b * TQ + q0 + r) * TV + seg*256;
        #pragma unroll
        for (int t = 0; t < 4; ++t) arow[t*64 + lane] = s[t] * inv;
    }
}

// ---------------- context = attn @ value via bf16-split MFMA (UNCHANGED) ----------------
__global__ __launch_bounds__(256, 2)
void ctx_kernel(const float* __restrict__ attn,
                const unsigned short* __restrict__ vht, const unsigned short* __restrict__ vlt,
                float* __restrict__ ctx){
    __shared__ unsigned short Ah[32*64], Al[32*64], Vh[64*64], Vl[64*64];

    const int m0   = blockIdx.x * 32;
    const int n0   = blockIdx.y * 64;
    const int b    = m0 >> 10;
    const int tid  = threadIdx.x;
    const int lane = tid & 63;
    const int w    = tid >> 6;

    const int am = tid >> 3;
    const int kq = (tid & 7) * 8;
    const int cn = tid >> 2;
    const int kv = (tid & 3) * 16;

    const float*          arow  = attn + (size_t)(m0 + am) * TV;
    const unsigned short* vhrow = vht + ((size_t)b * DD + n0 + cn) * TV;
    const unsigned short* vlrow = vlt + ((size_t)b * DD + n0 + cn) * TV;

    float ra[8];
    int4 rvh0, rvh1, rvl0, rvl1;
    #pragma unroll
    for (int i = 0; i < 2; ++i)
        *reinterpret_cast<float4*>(&ra[i*4]) = *reinterpret_cast<const float4*>(arow + kq + i*4);
    rvh0 = *reinterpret_cast<const int4*>(vhrow + kv);
    rvh1 = *reinterpret_cast<const int4*>(vhrow + kv + 8);
    rvl0 = *reinterpret_cast<const int4*>(vlrow + kv);
    rvl1 = *reinterpret_cast<const int4*>(vlrow + kv + 8);

    f32x4 acc[2];
    acc[0] = (f32x4){0.f,0.f,0.f,0.f};
    acc[1] = (f32x4){0.f,0.f,0.f,0.f};

    const int ga  = (kq >> 3) ^ (am & 7);
    const int gv0 = ((kv >> 3) + 0) ^ (cn & 7);
    const int gv1 = ((kv >> 3) + 1) ^ (cn & 7);

    for (int kt = 0; kt < TV; kt += 64){
        {
            unsigned short h8[8], l8[8];
            #pragma unroll
            for (int e = 0; e < 8; ++e){
                float a = ra[e];
                unsigned short h = f2bf(a);
                h8[e] = h; l8[e] = f2bf(a - bf2f(h));
            }
            *reinterpret_cast<int4*>(&Ah[am*64 + ga*8]) = *reinterpret_cast<const int4*>(h8);
            *reinterpret_cast<int4*>(&Al[am*64 + ga*8]) = *reinterpret_cast<const int4*>(l8);
        }
        *reinterpret_cast<int4*>(&Vh[cn*64 + gv0*8]) = rvh0;
        *reinterpret_cast<int4*>(&Vh[cn*64 + gv1*8]) = rvh1;
        *reinterpret_cast<int4*>(&Vl[cn*64 + gv0*8]) = rvl0;
        *reinterpret_cast<int4*>(&Vl[cn*64 + gv1*8]) = rvl1;

        const int ktn = (kt + 64 < TV) ? kt + 64 : 0;
        #pragma unroll
        for (int i = 0; i < 2; ++i)
            *reinterpret_cast<float4*>(&ra[i*4]) = *reinterpret_cast<const float4*>(arow + ktn + kq + i*4);
        rvh0 = *reinterpret_cast<const int4*>(vhrow + ktn + kv);
        rvh1 = *reinterpret_cast<const int4*>(vhrow + ktn + kv + 8);
        rvl0 = *reinterpret_cast<const int4*>(vlrow + ktn + kv);
        rvl1 = *reinterpret_cast<const int4*>(vlrow + ktn + kv + 8);

        __syncthreads();

        #pragma unroll
        for (int kk = 0; kk < 2; ++kk){
            const int kg = kk*4 + (lane >> 4);
            const int g  = (kg ^ (lane & 7)) * 8;
            const int r0 = (lane & 15) * 64;
            const int c0 = (w*16 + (lane & 15)) * 64;

            short8 a0h = *reinterpret_cast<const short8*>(&Ah[r0 + g]);
            short8 a1h = *reinterpret_cast<const short8*>(&Ah[r0 + 16*64 + g]);
            short8 a0l = *reinterpret_cast<const short8*>(&Al[r0 + g]);
            short8 a1l = *reinterpret_cast<const short8*>(&Al[r0 + 16*64 + g]);
            short8 bh  = *reinterpret_cast<const short8*>(&Vh[c0 + g]);
            short8 bl  = *reinterpret_cast<const short8*>(&Vl[c0 + g]);

            acc[0] = __builtin_amdgcn_mfma_f32_16x16x32_bf16(a0h, bh, acc[0], 0, 0, 0);
            acc[0] = __builtin_amdgcn_mfma_f32_16x16x32_bf16(a0l, bh, acc[0], 0, 0, 0);
            acc[0] = __builtin_amdgcn_mfma_f32_16x16x32_bf16(a0h, bl, acc[0], 0, 0, 0);

            acc[1] = __builtin_amdgcn_mfma_f32_16x16x32_bf16(a1h, bh, acc[1], 0, 0, 0);
            acc[1] = __builtin_amdgcn_mfma_f32_16x16x32_bf16(a1l, bh, acc[1], 0, 0, 0);
            acc[1] = __builtin_amdgcn_mfma_f32_16x16x32_bf16(a1h, bl, acc[1], 0, 0, 0);
        }

        __syncthreads();
    }

    #pragma unroll
    for (int fm = 0; fm < 2; ++fm){
        const int row = m0 + fm*16 + (lane >> 4) * 4;
        const int col = n0 + w*16 + (lane & 15);
        #pragma unroll
        for (int r = 0; r < 4; ++r)
            ctx[(size_t)(row + r) * DD + col] = acc[fm][r];
    }
}

extern "C" void kernel_launch(void* const* d_in, const int* in_sizes, int n_in,
                              void* d_out, int out_size, void* d_ws, size_t ws_size,
                              hipStream_t stream){
    const float* query = (const float*)d_in[0];
    const float* value = (const float*)d_in[1];
    const float* W1    = (const float*)d_in[2];
    const float* W2    = (const float*)d_in[3];
    const float* scale = (const float*)d_in[4];

    float* eq = (float*)d_ws;                              // 1 MB
    float* ek = eq + (size_t)B_ * TQ * UU;                 // 1 MB
    unsigned short* vht = (unsigned short*)(ek + (size_t)B_ * TV * UU);   // 2 MB
    unsigned short* vlt = vht + (size_t)B_ * DD * TV;                     // 2 MB
    unsigned short* wth = vlt + (size_t)B_ * DD * TV;                     // 256 KB
    unsigned short* wtl = wth + (size_t)2 * UU * DD;                      // 256 KB

    float* out  = (float*)d_out;
    float* ctx  = out;                                     // [B][TQ][DD]
    float* attn = out + (size_t)B_ * TQ * DD;              // [B][TQ][TV]

    wsplit_kernel<<<32, 256, 0, stream>>>(W1, W2, wth, wtl);
    projv_kernel<<<768, 256, 0, stream>>>(query, value, wth, wtl, vht, vlt, eq, ek);
    fused_kernel<<<dim3(TQ/QB, B_), 1024, 0, stream>>>(eq, ek, scale, attn);
    ctx_kernel<<<dim3((B_*TQ)/32, DD/64), 256, 0, stream>>>(attn, vht, vlt, ctx);
}

// Round 25
// 64.688 us; speedup vs baseline: 1.0595x; 1.0595x over previous
//
#include <hip/hip_runtime.h>

#define B_  2
#define TQ  1024
#define TV  1024
#define DD  512
#define UU  128

#define QB  4            // q-rows per fused block

typedef __attribute__((ext_vector_type(8))) short short8;
typedef __attribute__((ext_vector_type(4))) float f32x4;
typedef __attribute__((ext_vector_type(2))) float f32x2;

__device__ __forceinline__ unsigned short f2bf(float x){
    unsigned int u = __float_as_uint(x);
    unsigned int r = (u + 0x7FFFu + ((u >> 16) & 1u)) >> 16;
    return (unsigned short)r;
}
__device__ __forceinline__ float bf2f(unsigned short h){
    return __uint_as_float(((unsigned int)h) << 16);
}

// ---------------- W transpose + bf16 h/l split (tiny, runs first) ----------------
__global__ __launch_bounds__(256)
void wsplit_kernel(const float* __restrict__ W1, const float* __restrict__ W2,
                   unsigned short* __restrict__ wth, unsigned short* __restrict__ wtl){
    __shared__ float t[64][65];
    const int wb  = blockIdx.x;
    const int qk  = wb >> 4;
    const int rem = wb & 15;
    const int k0  = (rem >> 1) * 64;
    const int u0  = (rem & 1) * 64;
    const float* W = qk ? W2 : W1;
    const int tid = threadIdx.x;

    #pragma unroll
    for (int i = 0; i < 4; ++i){
        int r = (tid >> 4) + 16*i;
        int c = (tid & 15) * 4;
        float4 v = *reinterpret_cast<const float4*>(W + (size_t)(k0 + r)*UU + u0 + c);
        t[r][c+0]=v.x; t[r][c+1]=v.y; t[r][c+2]=v.z; t[r][c+3]=v.w;
    }
    __syncthreads();

    const int dr = tid >> 2;
    const int kc = (tid & 3) * 16;
    #pragma unroll
    for (int g = 0; g < 2; ++g){
        unsigned short h8[8], l8[8];
        #pragma unroll
        for (int e = 0; e < 8; ++e){
            float v = t[kc + g*8 + e][dr];
            unsigned short h = f2bf(v);
            h8[e] = h; l8[e] = f2bf(v - bf2f(h));
        }
        size_t o = ((size_t)qk*UU + u0 + dr)*(size_t)DD + k0 + kc + g*8;
        *reinterpret_cast<int4*>(wth + o) = *reinterpret_cast<const int4*>(h8);
        *reinterpret_cast<int4*>(wtl + o) = *reinterpret_cast<const int4*>(l8);
    }
}

// ---------------- merged: vsplit (blocks 0..255) + projm (blocks 256..767) ----------------
__global__ __launch_bounds__(256, 4)
void projv_kernel(const float* __restrict__ query, const float* __restrict__ value,
                  const unsigned short* __restrict__ wth, const unsigned short* __restrict__ wtl,
                  unsigned short* __restrict__ vht, unsigned short* __restrict__ vlt,
                  float* __restrict__ eq, float* __restrict__ ek){
    __shared__ char smem[20608];
    const int bid = blockIdx.x;
    const int tid = threadIdx.x;

    if (bid < 256){
        // ---- vsplit ----
        float (*t)[65] = reinterpret_cast<float(*)[65]>(smem);
        const int b   = bid >> 7;
        const int rem = bid & 127;
        const int k0  = (rem >> 3) * 64;
        const int d0  = (rem & 7) * 64;

        #pragma unroll
        for (int i = 0; i < 4; ++i){
            int r = (tid >> 4) + 16*i;
            int c = (tid & 15) * 4;
            float4 v = *reinterpret_cast<const float4*>(value + ((size_t)b*TV + k0 + r)*DD + d0 + c);
            t[r][c+0]=v.x; t[r][c+1]=v.y; t[r][c+2]=v.z; t[r][c+3]=v.w;
        }
        __syncthreads();

        const int dr = tid >> 2;
        const int kc = (tid & 3) * 16;
        #pragma unroll
        for (int g = 0; g < 2; ++g){
            unsigned short h8[8], l8[8];
            #pragma unroll
            for (int e = 0; e < 8; ++e){
                float v = t[kc + g*8 + e][dr];
                unsigned short h = f2bf(v);
                h8[e] = h; l8[e] = f2bf(v - bf2f(h));
            }
            size_t o = ((size_t)b*DD + d0 + dr)*(size_t)TV + k0 + kc + g*8;
            *reinterpret_cast<int4*>(vht + o) = *reinterpret_cast<const int4*>(h8);
            *reinterpret_cast<int4*>(vlt + o) = *reinterpret_cast<const int4*>(l8);
        }
        return;
    }

    // ---- projm ----
    unsigned short* Ah = reinterpret_cast<unsigned short*>(smem);
    unsigned short* Al = Ah + 16*64;
    unsigned short* Bh = Al + 16*64;
    unsigned short* Bl = Bh + 64*64;

    const float TWO_LOG2E = 2.8853900817779268f;
    const int pb  = bid - 256;
    const int qk  = pb >> 8;
    const int rem = pb & 255;
    const int r0g = (rem >> 1) * 16;
    const int n0  = (rem & 1) * 64;
    const float* X = qk ? value : query;
    float* out     = qk ? ek    : eq;
    const unsigned short* WH = wth + (size_t)qk * UU * DD;
    const unsigned short* WL = wtl + (size_t)qk * UU * DD;

    const int lane = tid & 63;
    const int w    = tid >> 6;

    const int ar  = tid >> 4;
    const int akq = (tid & 15) * 4;
    const int bc  = tid >> 2;
    const int bkc = (tid & 3) * 16;

    const float*          xrow  = X + (size_t)(r0g + ar) * DD;
    const unsigned short* whrow = WH + (size_t)(n0 + bc) * DD;
    const unsigned short* wlrow = WL + (size_t)(n0 + bc) * DD;

    float4 ra = *reinterpret_cast<const float4*>(xrow + akq);
    int4 rwh0 = *reinterpret_cast<const int4*>(whrow + bkc);
    int4 rwh1 = *reinterpret_cast<const int4*>(whrow + bkc + 8);
    int4 rwl0 = *reinterpret_cast<const int4*>(wlrow + bkc);
    int4 rwl1 = *reinterpret_cast<const int4*>(wlrow + bkc + 8);

    f32x4 acc = (f32x4){0.f,0.f,0.f,0.f};

    const int ga  = (akq >> 3) ^ (ar & 7);
    const int ao  = akq & 7;
    const int gb0 = ((bkc >> 3) + 0) ^ (bc & 7);
    const int gb1 = ((bkc >> 3) + 1) ^ (bc & 7);

    for (int kt = 0; kt < DD; kt += 64){
        {
            unsigned short h4[4], l4[4];
            #pragma unroll
            for (int e = 0; e < 4; ++e){
                float a = (e==0)?ra.x:(e==1)?ra.y:(e==2)?ra.z:ra.w;
                unsigned short h = f2bf(a);
                h4[e] = h; l4[e] = f2bf(a - bf2f(h));
            }
            *reinterpret_cast<int2*>(&Ah[ar*64 + ga*8 + ao]) = *reinterpret_cast<const int2*>(h4);
            *reinterpret_cast<int2*>(&Al[ar*64 + ga*8 + ao]) = *reinterpret_cast<const int2*>(l4);
        }
        *reinterpret_cast<int4*>(&Bh[bc*64 + gb0*8]) = rwh0;
        *reinterpret_cast<int4*>(&Bh[bc*64 + gb1*8]) = rwh1;
        *reinterpret_cast<int4*>(&Bl[bc*64 + gb0*8]) = rwl0;
        *reinterpret_cast<int4*>(&Bl[bc*64 + gb1*8]) = rwl1;

        const int ktn = (kt + 64 < DD) ? kt + 64 : 0;
        ra   = *reinterpret_cast<const float4*>(xrow + ktn + akq);
        rwh0 = *reinterpret_cast<const int4*>(whrow + ktn + bkc);
        rwh1 = *reinterpret_cast<const int4*>(whrow + ktn + bkc + 8);
        rwl0 = *reinterpret_cast<const int4*>(wlrow + ktn + bkc);
        rwl1 = *reinterpret_cast<const int4*>(wlrow + ktn + bkc + 8);

        __syncthreads();

        #pragma unroll
        for (int kk = 0; kk < 2; ++kk){
            const int kg = kk*4 + (lane >> 4);
            const int g  = (kg ^ (lane & 7)) * 8;
            const int r0 = (lane & 15) * 64;
            const int c0 = (w*16 + (lane & 15)) * 64;

            short8 ah = *reinterpret_cast<const short8*>(&Ah[r0 + g]);
            short8 al = *reinterpret_cast<const short8*>(&Al[r0 + g]);
            short8 bh = *reinterpret_cast<const short8*>(&Bh[c0 + g]);
            short8 bl = *reinterpret_cast<const short8*>(&Bl[c0 + g]);

            acc = __builtin_amdgcn_mfma_f32_16x16x32_bf16(ah, bh, acc, 0, 0, 0);
            acc = __builtin_amdgcn_mfma_f32_16x16x32_bf16(al, bh, acc, 0, 0, 0);
            acc = __builtin_amdgcn_mfma_f32_16x16x32_bf16(ah, bl, acc, 0, 0, 0);
        }

        __syncthreads();
    }

    const int orow = r0g + (lane >> 4) * 4;
    const int ocol = n0 + w*16 + (lane & 15);
    #pragma unroll
    for (int r = 0; r < 4; ++r)
        out[(size_t)(orow + r) * UU + ocol] = __builtin_amdgcn_exp2f(TWO_LOG2E * acc[r]);
}

// ---------------- fused scores + softmax, packed f32x2 vector arithmetic ----------------
// score[q,k] = -2 * sum_u scale[u] * rcp(1 + EQ[q,u]*EK[k,u])  (+const, cancels in softmax)
// Packed math expressed as ext_vector C ops -> compiler emits v_pk_fma_f32.
__global__ __launch_bounds__(1024, 8)
void fused_kernel(const float* __restrict__ eq, const float* __restrict__ ek,
                  const float* __restrict__ scale, float* __restrict__ attn){
    __shared__ float sm[QB][TV];
    __shared__ float psum[QB][4];

    const float LOG2E = 1.4426950408889634f;
    const int b   = blockIdx.y;
    const int q0  = blockIdx.x * QB;
    const int tid = threadIdx.x;
    const int w   = tid >> 6, lane = tid & 63;

    const f32x2* q0v = reinterpret_cast<const f32x2*>(eq + ((size_t)b * TQ + q0 + 0) * UU);
    const f32x2* q1v = reinterpret_cast<const f32x2*>(eq + ((size_t)b * TQ + q0 + 1) * UU);
    const f32x2* q2v = reinterpret_cast<const f32x2*>(eq + ((size_t)b * TQ + q0 + 2) * UU);
    const f32x2* q3v = reinterpret_cast<const f32x2*>(eq + ((size_t)b * TQ + q0 + 3) * UU);
    const f32x2* sc2 = reinterpret_cast<const f32x2*>(scale);

    const float4* ekv = reinterpret_cast<const float4*>(ek + (size_t)b * TV * UU);

    const int kA = w*64 + lane;
    const size_t iA = (size_t)kA * 32;

    f32x2 acc2[QB];
    #pragma unroll
    for (int r = 0; r < QB; ++r) acc2[r] = (f32x2){0.f, 0.f};
    const f32x2 one2 = (f32x2){1.0f, 1.0f};

    float4 kva = ekv[iA];

    for (int j = 0; j < 32; ++j){
        float4 nka;
        if (j != 31) nka = ekv[iA + j + 1];
        f32x2 sxy = sc2[2*j], szw = sc2[2*j+1];
        f32x2 kxy, kzw;
        kxy.x = kva.x; kxy.y = kva.y;
        kzw.x = kva.z; kzw.y = kva.w;
        #pragma unroll
        for (int r = 0; r < QB; ++r){
            const f32x2* qv = (r==0)?q0v:(r==1)?q1v:(r==2)?q2v:q3v;
            f32x2 q, t, rr;
            q = qv[2*j];
            t = q * kxy + one2;
            rr.x = __builtin_amdgcn_rcpf(t.x);
            rr.y = __builtin_amdgcn_rcpf(t.y);
            acc2[r] += sxy * rr;
            q = qv[2*j+1];
            t = q * kzw + one2;
            rr.x = __builtin_amdgcn_rcpf(t.x);
            rr.y = __builtin_amdgcn_rcpf(t.y);
            acc2[r] += szw * rr;
        }
        kva = nka;
    }

    #pragma unroll
    for (int r = 0; r < QB; ++r) sm[r][kA] = -2.0f * (acc2[r].x + acc2[r].y);
    __syncthreads();

    // no-max softmax: wave w -> row r = w&3, segment seg = w>>2 (256 k)
    {
        const int r   = w & 3;
        const int seg = w >> 2;
        float s[4];
        #pragma unroll
        for (int t = 0; t < 4; ++t) s[t] = sm[r][seg*256 + t*64 + lane];

        float sum = 0.f;
        #pragma unroll
        for (int t = 0; t < 4; ++t){ s[t] = __builtin_amdgcn_exp2f(s[t] * LOG2E); sum += s[t]; }
        #pragma unroll
        for (int off = 32; off >= 1; off >>= 1) sum += __shfl_xor(sum, off, 64);
        if (lane == 0) psum[r][seg] = sum;
        __syncthreads();

        float S = (psum[r][0] + psum[r][1]) + (psum[r][2] + psum[r][3]);
        float inv = 1.0f / S;

        float* arow = attn + ((size_t)b * TQ + q0 + r) * TV + seg*256;
        #pragma unroll
        for (int t = 0; t < 4; ++t) arow[t*64 + lane] = s[t] * inv;
    }
}

// ---------------- context = attn @ value via bf16-split MFMA (UNCHANGED) ----------------
__global__ __launch_bounds__(256, 2)
void ctx_kernel(const float* __restrict__ attn,
                const unsigned short* __restrict__ vht, const unsigned short* __restrict__ vlt,
                float* __restrict__ ctx){
    __shared__ unsigned short Ah[32*64], Al[32*64], Vh[64*64], Vl[64*64];

    const int m0   = blockIdx.x * 32;
    const int n0   = blockIdx.y * 64;
    const int b    = m0 >> 10;
    const int tid  = threadIdx.x;
    const int lane = tid & 63;
    const int w    = tid >> 6;

    const int am = tid >> 3;
    const int kq = (tid & 7) * 8;
    const int cn = tid >> 2;
    const int kv = (tid & 3) * 16;

    const float*          arow  = attn + (size_t)(m0 + am) * TV;
    const unsigned short* vhrow = vht + ((size_t)b * DD + n0 + cn) * TV;
    const unsigned short* vlrow = vlt + ((size_t)b * DD + n0 + cn) * TV;

    float ra[8];
    int4 rvh0, rvh1, rvl0, rvl1;
    #pragma unroll
    for (int i = 0; i < 2; ++i)
        *reinterpret_cast<float4*>(&ra[i*4]) = *reinterpret_cast<const float4*>(arow + kq + i*4);
    rvh0 = *reinterpret_cast<const int4*>(vhrow + kv);
    rvh1 = *reinterpret_cast<const int4*>(vhrow + kv + 8);
    rvl0 = *reinterpret_cast<const int4*>(vlrow + kv);
    rvl1 = *reinterpret_cast<const int4*>(vlrow + kv + 8);

    f32x4 acc[2];
    acc[0] = (f32x4){0.f,0.f,0.f,0.f};
    acc[1] = (f32x4){0.f,0.f,0.f,0.f};

    const int ga  = (kq >> 3) ^ (am & 7);
    const int gv0 = ((kv >> 3) + 0) ^ (cn & 7);
    const int gv1 = ((kv >> 3) + 1) ^ (cn & 7);

    for (int kt = 0; kt < TV; kt += 64){
        {
            unsigned short h8[8], l8[8];
            #pragma unroll
            for (int e = 0; e < 8; ++e){
                float a = ra[e];
                unsigned short h = f2bf(a);
                h8[e] = h; l8[e] = f2bf(a - bf2f(h));
            }
            *reinterpret_cast<int4*>(&Ah[am*64 + ga*8]) = *reinterpret_cast<const int4*>(h8);
            *reinterpret_cast<int4*>(&Al[am*64 + ga*8]) = *reinterpret_cast<const int4*>(l8);
        }
        *reinterpret_cast<int4*>(&Vh[cn*64 + gv0*8]) = rvh0;
        *reinterpret_cast<int4*>(&Vh[cn*64 + gv1*8]) = rvh1;
        *reinterpret_cast<int4*>(&Vl[cn*64 + gv0*8]) = rvl0;
        *reinterpret_cast<int4*>(&Vl[cn*64 + gv1*8]) = rvl1;

        const int ktn = (kt + 64 < TV) ? kt + 64 : 0;
        #pragma unroll
        for (int i = 0; i < 2; ++i)
            *reinterpret_cast<float4*>(&ra[i*4]) = *reinterpret_cast<const float4*>(arow + ktn + kq + i*4);
        rvh0 = *reinterpret_cast<const int4*>(vhrow + ktn + kv);
        rvh1 = *reinterpret_cast<const int4*>(vhrow + ktn + kv + 8);
        rvl0 = *reinterpret_cast<const int4*>(vlrow + ktn + kv);
        rvl1 = *reinterpret_cast<const int4*>(vlrow + ktn + kv + 8);

        __syncthreads();

        #pragma unroll
        for (int kk = 0; kk < 2; ++kk){
            const int kg = kk*4 + (lane >> 4);
            const int g  = (kg ^ (lane & 7)) * 8;
            const int r0 = (lane & 15) * 64;
            const int c0 = (w*16 + (lane & 15)) * 64;

            short8 a0h = *reinterpret_cast<const short8*>(&Ah[r0 + g]);
            short8 a1h = *reinterpret_cast<const short8*>(&Ah[r0 + 16*64 + g]);
            short8 a0l = *reinterpret_cast<const short8*>(&Al[r0 + g]);
            short8 a1l = *reinterpret_cast<const short8*>(&Al[r0 + 16*64 + g]);
            short8 bh  = *reinterpret_cast<const short8*>(&Vh[c0 + g]);
            short8 bl  = *reinterpret_cast<const short8*>(&Vl[c0 + g]);

            acc[0] = __builtin_amdgcn_mfma_f32_16x16x32_bf16(a0h, bh, acc[0], 0, 0, 0);
            acc[0] = __builtin_amdgcn_mfma_f32_16x16x32_bf16(a0l, bh, acc[0], 0, 0, 0);
            acc[0] = __builtin_amdgcn_mfma_f32_16x16x32_bf16(a0h, bl, acc[0], 0, 0, 0);

            acc[1] = __builtin_amdgcn_mfma_f32_16x16x32_bf16(a1h, bh, acc[1], 0, 0, 0);
            acc[1] = __builtin_amdgcn_mfma_f32_16x16x32_bf16(a1l, bh, acc[1], 0, 0, 0);
            acc[1] = __builtin_amdgcn_mfma_f32_16x16x32_bf16(a1h, bl, acc[1], 0, 0, 0);
        }

        __syncthreads();
    }

    #pragma unroll
    for (int fm = 0; fm < 2; ++fm){
        const int row = m0 + fm*16 + (lane >> 4) * 4;
        const int col = n0 + w*16 + (lane & 15);
        #pragma unroll
        for (int r = 0; r < 4; ++r)
            ctx[(size_t)(row + r) * DD + col] = acc[fm][r];
    }
}

extern "C" void kernel_launch(void* const* d_in, const int* in_sizes, int n_in,
                              void* d_out, int out_size, void* d_ws, size_t ws_size,
                              hipStream_t stream){
    const float* query = (const float*)d_in[0];
    const float* value = (const float*)d_in[1];
    const float* W1    = (const float*)d_in[2];
    const float* W2    = (const float*)d_in[3];
    const float* scale = (const float*)d_in[4];

    float* eq = (float*)d_ws;                              // 1 MB
    float* ek = eq + (size_t)B_ * TQ * UU;                 // 1 MB
    unsigned short* vht = (unsigned short*)(ek + (size_t)B_ * TV * UU);   // 2 MB
    unsigned short* vlt = vht + (size_t)B_ * DD * TV;                     // 2 MB
    unsigned short* wth = vlt + (size_t)B_ * DD * TV;                     // 256 KB
    unsigned short* wtl = wth + (size_t)2 * UU * DD;                      // 256 KB

    float* out  = (float*)d_out;
    float* ctx  = out;                                     // [B][TQ][DD]
    float* attn = out + (size_t)B_ * TQ * DD;              // [B][TQ][TV]

    wsplit_kernel<<<32, 256, 0, stream>>>(W1, W2, wth, wtl);
    projv_kernel<<<768, 256, 0, stream>>>(query, value, wth, wtl, vht, vlt, eq, ek);
    fused_kernel<<<dim3(TQ/QB, B_), 1024, 0, stream>>>(eq, ek, scale, attn);
    ctx_kernel<<<dim3((B_*TQ)/32, DD/64), 256, 0, stream>>>(attn, vht, vlt, ctx);
}